// Round 2
// baseline (4310.241 us; speedup 1.0000x reference)
//
#include <hip/hip_runtime.h>
#include <hip/hip_bf16.h>
#include <math.h>

typedef __hip_bfloat16 bf16;

#define BB 4
#define LL 1024
#define DD 768
#define HH 12
#define DK 64
#define FF_ 3072
#define PP 32
#define MAXD 256

__device__ inline float to_f(const bf16 v) { return __bfloat162float(v); }
__device__ inline float to_f(const float v) { return v; }

// ---------------- LayerNorm ----------------
// one block (256 threads) per row of 768; fp32 in, bf16 out
template <typename InT>
__global__ __launch_bounds__(256) void ln_kernel(const InT* __restrict__ x,
                                                 const float* __restrict__ g,
                                                 const float* __restrict__ b,
                                                 float eps,
                                                 bf16* __restrict__ y) {
    const int row = blockIdx.x;
    const int tid = threadIdx.x;
    const InT* xr = x + (size_t)row * DD;

    float v[3];
    float s = 0.f, ss = 0.f;
#pragma unroll
    for (int i = 0; i < 3; ++i) {
        float t = to_f(xr[tid + i * 256]);
        v[i] = t;
        s += t;
        ss += t * t;
    }
    __shared__ float rs[256], rss[256];
    rs[tid] = s; rss[tid] = ss;
    __syncthreads();
    for (int off = 128; off; off >>= 1) {
        if (tid < off) { rs[tid] += rs[tid + off]; rss[tid] += rss[tid + off]; }
        __syncthreads();
    }
    const float mean = rs[0] * (1.f / DD);
    const float var  = rss[0] * (1.f / DD) - mean * mean;
    const float inv  = rsqrtf(var + eps);
#pragma unroll
    for (int i = 0; i < 3; ++i) {
        int c = tid + i * 256;
        float o = (v[i] - mean) * inv * g[c] + b[c];
        y[(size_t)row * DD + c] = __float2bfloat16(o);
    }
}

// ---------------- Tiled GEMM: C[M,N] = act(A[M,K] @ W[K,N] + bias) (+ res) ----------------
// RES: 0 none, 2 f32 residual.
template <int RES, bool GELU, typename AT, typename OutT>
__global__ __launch_bounds__(256) void gemm_kernel(const AT* __restrict__ A,
                                                   const float* __restrict__ W,
                                                   const float* __restrict__ bias,
                                                   const float* __restrict__ res,
                                                   OutT* __restrict__ C,
                                                   int M, int N, int K) {
    __shared__ float As[16][64 + 1];
    __shared__ float Bs[16][64 + 1];
    const int bm = blockIdx.y * 64;
    const int bn = blockIdx.x * 64;
    const int tid = threadIdx.x;
    const int tx = tid & 15;   // n dimension
    const int ty = tid >> 4;   // m dimension

    float acc[4][4] = {};

    for (int k0 = 0; k0 < K; k0 += 16) {
        // load A tile 64(m) x 16(k)
#pragma unroll
        for (int t = tid; t < 1024; t += 256) {
            int m = t >> 4, k = t & 15;
            As[k][m] = to_f(A[(size_t)(bm + m) * K + k0 + k]);
        }
        // load W tile 16(k) x 64(n)
#pragma unroll
        for (int t = tid; t < 1024; t += 256) {
            int k = t >> 6, n = t & 63;
            Bs[k][n] = W[(size_t)(k0 + k) * N + bn + n];
        }
        __syncthreads();
#pragma unroll
        for (int k = 0; k < 16; ++k) {
            float a[4], bv[4];
#pragma unroll
            for (int i = 0; i < 4; ++i) a[i] = As[k][ty * 4 + i];
#pragma unroll
            for (int j = 0; j < 4; ++j) bv[j] = Bs[k][tx * 4 + j];
#pragma unroll
            for (int i = 0; i < 4; ++i)
#pragma unroll
                for (int j = 0; j < 4; ++j)
                    acc[i][j] += a[i] * bv[j];
        }
        __syncthreads();
    }

#pragma unroll
    for (int i = 0; i < 4; ++i) {
        const int m = bm + ty * 4 + i;
#pragma unroll
        for (int j = 0; j < 4; ++j) {
            const int n = bn + tx * 4 + j;
            float v = acc[i][j] + bias[n];
            if (GELU) v = 0.5f * v * (1.f + erff(v * 0.70710678118f));
            if (RES == 2) v += res[(size_t)m * N + n];
            if constexpr (sizeof(OutT) == 2)
                C[(size_t)m * N + n] = __float2bfloat16(v);
            else
                C[(size_t)m * N + n] = v;
        }
    }
}

// ---------------- Attention: one block per (b,h,l) ----------------
__global__ __launch_bounds__(128) void attn_kernel(const bf16* __restrict__ Q,
                                                   const bf16* __restrict__ K,
                                                   const bf16* __restrict__ V,
                                                   const int* __restrict__ postag,
                                                   const float* __restrict__ lex,
                                                   const float* __restrict__ rel_emb,
                                                   const float* __restrict__ pt_table,
                                                   bf16* __restrict__ O) {
    const int l = blockIdx.x;
    const int h = blockIdx.y;
    const int b = blockIdx.z;
    const int tid = threadIdx.x;

    __shared__ float q[64];
    __shared__ float p[LL];
    __shared__ float red[128];

    if (tid < 64)
        q[tid] = to_f(Q[((size_t)(b * LL + l)) * DD + h * DK + tid]);
    const int pl = postag[b * LL + l];
    __syncthreads();

    // logits + biases
    float lmax = -1e30f;
    for (int s = tid; s < LL; s += 128) {
        const bf16* kr = K + ((size_t)(b * LL + s)) * DD + h * DK;
        float acc = 0.f;
#pragma unroll
        for (int d = 0; d < DK; ++d) acc += q[d] * to_f(kr[d]);
        int relc = min(max(s - l, -MAXD), MAXD) + MAXD;
        int ps = postag[b * LL + s];
        float logit = acc * 0.125f
            + rel_emb[relc * HH + h]
            + pt_table[(pl * PP + ps) * HH + h]
            + lex[b * LL + s];
        p[s] = logit;
        lmax = fmaxf(lmax, logit);
    }
    red[tid] = lmax;
    __syncthreads();
    for (int off = 64; off; off >>= 1) {
        if (tid < off) red[tid] = fmaxf(red[tid], red[tid + off]);
        __syncthreads();
    }
    const float m = red[0];
    __syncthreads();

    float lsum = 0.f;
    for (int s = tid; s < LL; s += 128) {
        float e = expf(p[s] - m);
        p[s] = e;
        lsum += e;
    }
    red[tid] = lsum;
    __syncthreads();
    for (int off = 64; off; off >>= 1) {
        if (tid < off) red[tid] += red[tid + off];
        __syncthreads();
    }
    const float inv = 1.f / red[0];
    __syncthreads();

    // PV: tid -> (d = tid&63, half = tid>>6)
    const int d = tid & 63;
    const int half = tid >> 6;
    float acc = 0.f;
    for (int s = half * 512; s < half * 512 + 512; ++s)
        acc += p[s] * to_f(V[((size_t)(b * LL + s)) * DD + h * DK + d]);
    red[tid] = acc;
    __syncthreads();
    if (tid < 64) {
        float o = (red[tid] + red[tid + 64]) * inv;
        O[((size_t)(b * LL + l)) * DD + h * DK + tid] = __float2bfloat16(o);
    }
}

extern "C" void kernel_launch(void* const* d_in, const int* in_sizes, int n_in,
                              void* d_out, int out_size, void* d_ws, size_t ws_size,
                              hipStream_t stream) {
    const float* x          = (const float*)d_in[0];
    const int*   postag_ids = (const int*)d_in[1];
    const float* lex_mask   = (const float*)d_in[2];
    const float* ln1_g      = (const float*)d_in[3];
    const float* ln1_b      = (const float*)d_in[4];
    const float* Wq         = (const float*)d_in[5];
    const float* bq         = (const float*)d_in[6];
    const float* Wk         = (const float*)d_in[7];
    const float* bk         = (const float*)d_in[8];
    const float* Wv         = (const float*)d_in[9];
    const float* bv         = (const float*)d_in[10];
    const float* Wo         = (const float*)d_in[11];
    const float* bo         = (const float*)d_in[12];
    const float* rel_emb    = (const float*)d_in[13];
    const float* pt_table   = (const float*)d_in[14];
    const float* ln2_g      = (const float*)d_in[15];
    const float* ln2_b      = (const float*)d_in[16];
    const float* W1         = (const float*)d_in[17];
    const float* b1         = (const float*)d_in[18];
    const float* W2         = (const float*)d_in[19];
    const float* b2         = (const float*)d_in[20];

    const int M = BB * LL;            // 4096
    char* ws = (char*)d_ws;
    size_t off = 0;
    bf16* y_ln = (bf16*)(ws + off); off += (size_t)M * DD * 2;       // 6.29MB
    bf16* Qm   = (bf16*)(ws + off); off += (size_t)M * DD * 2;
    bf16* Km   = (bf16*)(ws + off); off += (size_t)M * DD * 2;
    bf16* Vm   = (bf16*)(ws + off); off += (size_t)M * DD * 2;
    bf16* attn = (bf16*)(ws + off); off += (size_t)M * DD * 2;
    bf16* h2   = (bf16*)(ws + off); off += (size_t)M * DD * 2;
    float* out1 = (float*)(ws + off); off += (size_t)M * DD * 4;     // fp32 residual base
    bf16* ff1  = (bf16*)(ws + off); off += (size_t)M * FF_ * 2;      // 25.2MB

    // 1. LN1 (fp32 in, bf16 out)
    ln_kernel<float><<<M, 256, 0, stream>>>(x, ln1_g, ln1_b, 1e-6f, y_ln);

    // 2. Q,K,V projections (bf16 A, fp32 W, bf16 out)
    dim3 gD(DD / 64, M / 64);
    gemm_kernel<0, false, bf16, bf16><<<gD, 256, 0, stream>>>(y_ln, Wq, bq, nullptr, Qm, M, DD, DD);
    gemm_kernel<0, false, bf16, bf16><<<gD, 256, 0, stream>>>(y_ln, Wk, bk, nullptr, Km, M, DD, DD);
    gemm_kernel<0, false, bf16, bf16><<<gD, 256, 0, stream>>>(y_ln, Wv, bv, nullptr, Vm, M, DD, DD);

    // 3. attention with fused biases
    attn_kernel<<<dim3(LL, HH, BB), 128, 0, stream>>>(Qm, Km, Vm, postag_ids, lex_mask,
                                                      rel_emb, pt_table, attn);

    // 4. output projection + residual x  (fp32 out for LN2 + final residual)
    gemm_kernel<2, false, bf16, float><<<gD, 256, 0, stream>>>(attn, Wo, bo, x, out1, M, DD, DD);

    // 5. LN2 (fp32 in, bf16 out)
    ln_kernel<float><<<M, 256, 0, stream>>>(out1, ln2_g, ln2_b, 1e-5f, h2);

    // 6. FF1 + exact GELU (bf16 out)
    dim3 gF(FF_ / 64, M / 64);
    gemm_kernel<0, true, bf16, bf16><<<gF, 256, 0, stream>>>(h2, W1, b1, nullptr, ff1, M, FF_, DD);

    // 7. FF2 + residual(out1) -> d_out (fp32)
    gemm_kernel<2, false, bf16, float><<<gD, 256, 0, stream>>>(ff1, W2, b2, out1, (float*)d_out, M, DD, FF_);
}

// Round 3
// 1596.222 us; speedup vs baseline: 2.7003x; 2.7003x over previous
//
#include <hip/hip_runtime.h>
#include <hip/hip_bf16.h>
#include <math.h>

typedef __hip_bfloat16 bf16;
typedef __attribute__((ext_vector_type(8))) short short8;
typedef __attribute__((ext_vector_type(4))) float f32x4;
typedef __attribute__((ext_vector_type(4))) int int4v;

#define BB 4
#define LL 1024
#define DD 768
#define HH 12
#define DK 64
#define FF_ 3072
#define PP 32
#define MAXD 256

__device__ inline float to_f(const bf16 v) { return __bfloat162float(v); }
__device__ inline float to_f(const float v) { return v; }

// ---------------- LayerNorm ----------------
template <typename InT>
__global__ __launch_bounds__(256) void ln_kernel(const InT* __restrict__ x,
                                                 const float* __restrict__ g,
                                                 const float* __restrict__ b,
                                                 float eps,
                                                 bf16* __restrict__ y) {
    const int row = blockIdx.x;
    const int tid = threadIdx.x;
    const InT* xr = x + (size_t)row * DD;

    float v[3];
    float s = 0.f, ss = 0.f;
#pragma unroll
    for (int i = 0; i < 3; ++i) {
        float t = to_f(xr[tid + i * 256]);
        v[i] = t;
        s += t;
        ss += t * t;
    }
    __shared__ float rs[256], rss[256];
    rs[tid] = s; rss[tid] = ss;
    __syncthreads();
    for (int off = 128; off; off >>= 1) {
        if (tid < off) { rs[tid] += rs[tid + off]; rss[tid] += rss[tid + off]; }
        __syncthreads();
    }
    const float mean = rs[0] * (1.f / DD);
    const float var  = rss[0] * (1.f / DD) - mean * mean;
    const float inv  = rsqrtf(var + eps);
#pragma unroll
    for (int i = 0; i < 3; ++i) {
        int c = tid + i * 256;
        float o = (v[i] - mean) * inv * g[c] + b[c];
        y[(size_t)row * DD + c] = __float2bfloat16(o);
    }
}

// ---------------- Tiled scalar GEMM (unchanged from round 2) ----------------
template <int RES, bool GELU, typename AT, typename OutT>
__global__ __launch_bounds__(256) void gemm_kernel(const AT* __restrict__ A,
                                                   const float* __restrict__ W,
                                                   const float* __restrict__ bias,
                                                   const float* __restrict__ res,
                                                   OutT* __restrict__ C,
                                                   int M, int N, int K) {
    __shared__ float As[16][64 + 1];
    __shared__ float Bs[16][64 + 1];
    const int bm = blockIdx.y * 64;
    const int bn = blockIdx.x * 64;
    const int tid = threadIdx.x;
    const int tx = tid & 15;
    const int ty = tid >> 4;

    float acc[4][4] = {};

    for (int k0 = 0; k0 < K; k0 += 16) {
#pragma unroll
        for (int t = tid; t < 1024; t += 256) {
            int m = t >> 4, k = t & 15;
            As[k][m] = to_f(A[(size_t)(bm + m) * K + k0 + k]);
        }
#pragma unroll
        for (int t = tid; t < 1024; t += 256) {
            int k = t >> 6, n = t & 63;
            Bs[k][n] = W[(size_t)(k0 + k) * N + bn + n];
        }
        __syncthreads();
#pragma unroll
        for (int k = 0; k < 16; ++k) {
            float a[4], bv[4];
#pragma unroll
            for (int i = 0; i < 4; ++i) a[i] = As[k][ty * 4 + i];
#pragma unroll
            for (int j = 0; j < 4; ++j) bv[j] = Bs[k][tx * 4 + j];
#pragma unroll
            for (int i = 0; i < 4; ++i)
#pragma unroll
                for (int j = 0; j < 4; ++j)
                    acc[i][j] += a[i] * bv[j];
        }
        __syncthreads();
    }

#pragma unroll
    for (int i = 0; i < 4; ++i) {
        const int m = bm + ty * 4 + i;
#pragma unroll
        for (int j = 0; j < 4; ++j) {
            const int n = bn + tx * 4 + j;
            float v = acc[i][j] + bias[n];
            if (GELU) v = 0.5f * v * (1.f + erff(v * 0.70710678118f));
            if (RES == 2) v += res[(size_t)m * N + n];
            if constexpr (sizeof(OutT) == 2)
                C[(size_t)m * N + n] = __float2bfloat16(v);
            else
                C[(size_t)m * N + n] = v;
        }
    }
}

// ---------------- Flash attention with MFMA ----------------
// grid (16 q-tiles, 12 heads, 4 batch), 256 threads = 4 waves.
// Wave w owns q rows [qt*64 + w*16, +16). K-tiles of 64 iterated with online softmax.
// MFMA 16x16x32 bf16: A[m=lane&15][k=quad*8+j], B[n=lane&15][k=quad*8+j],
// C/D: col=lane&15, row=quad*4+reg.
__global__ __launch_bounds__(256) void flash_attn_kernel(
        const bf16* __restrict__ Q, const bf16* __restrict__ K, const bf16* __restrict__ V,
        const int* __restrict__ postag, const float* __restrict__ lex,
        const float* __restrict__ rel_emb, const float* __restrict__ pt_table,
        bf16* __restrict__ O) {
    const int qt = blockIdx.x;
    const int h  = blockIdx.y;
    const int b  = blockIdx.z;
    const int tid  = threadIdx.x;
    const int w    = tid >> 6;
    const int lane = tid & 63;
    const int c    = lane & 15;
    const int quad = lane >> 4;

    __shared__ short Vs[64][66];          // V tile [s][d], pad 66: ~conflict-free u16 frag reads
    __shared__ bf16  Ps[4][16][72];       // per-wave P [q][s], pad 72: 16B-aligned, 2-way free
    __shared__ float rel_col[513];        // rel_emb[:, h]
    __shared__ float pt_col[1024];        // pt_table[:, h]
    __shared__ float lex_t[64];
    __shared__ int   ps_t[64];

    for (int i = tid; i < 513; i += 256)  rel_col[i] = rel_emb[i * HH + h];
    for (int i = tid; i < 1024; i += 256) pt_col[i]  = pt_table[i * HH + h];

    const int q0 = qt * 64 + w * 16;      // wave q-row base within sequence

    // Q fragments (held for whole block)
    short8 qf[2];
    {
        const bf16* qp = Q + ((size_t)(b * LL + q0 + c)) * DD + h * DK + quad * 8;
        qf[0] = *(const short8*)qp;
        qf[1] = *(const short8*)(qp + 32);
    }
    // per-row (quad*4+reg) query postag
    int pl_r[4];
#pragma unroll
    for (int r = 0; r < 4; ++r) pl_r[r] = postag[b * LL + q0 + quad * 4 + r];

    float m_i[4], l_i[4];
#pragma unroll
    for (int r = 0; r < 4; ++r) { m_i[r] = -1e30f; l_i[r] = 0.f; }
    f32x4 o_acc[4];
#pragma unroll
    for (int t = 0; t < 4; ++t) o_acc[t] = (f32x4)0.f;

    for (int s0 = 0; s0 < LL; s0 += 64) {
        // ---- stage V tile (+ per-tile lex, postag) ----
#pragma unroll
        for (int it = 0; it < 2; ++it) {
            int i = it * 256 + tid;                 // 0..511
            int row = i >> 3, c8 = (i & 7) * 8;
            int4v v = *(const int4v*)(V + ((size_t)(b * LL + s0 + row)) * DD + h * DK + c8);
            int* dst = (int*)&Vs[row][c8];
            dst[0] = v.x; dst[1] = v.y; dst[2] = v.z; dst[3] = v.w;
        }
        if (tid < 64) {
            lex_t[tid] = lex[b * LL + s0 + tid];
            ps_t[tid]  = postag[b * LL + s0 + tid];
        }
        __syncthreads();

        // ---- K fragments direct from global (L2-resident) ----
        short8 kf[4][2];
#pragma unroll
        for (int t = 0; t < 4; ++t) {
            const bf16* kp = K + ((size_t)(b * LL + s0 + t * 16 + c)) * DD + h * DK + quad * 8;
            kf[t][0] = *(const short8*)kp;
            kf[t][1] = *(const short8*)(kp + 32);
        }

        // ---- S = Q K^T ----
        f32x4 S[4];
#pragma unroll
        for (int t = 0; t < 4; ++t) {
            f32x4 acc = (f32x4)0.f;
            acc = __builtin_amdgcn_mfma_f32_16x16x32_bf16(qf[0], kf[t][0], acc, 0, 0, 0);
            acc = __builtin_amdgcn_mfma_f32_16x16x32_bf16(qf[1], kf[t][1], acc, 0, 0, 0);
            S[t] = acc;
        }

        // ---- fused biases ----
#pragma unroll
        for (int t = 0; t < 4; ++t) {
            const int s_loc  = t * 16 + c;
            const float lx   = lex_t[s_loc];
            const int   ps   = ps_t[s_loc];
            const int s_glob = s0 + s_loc;
#pragma unroll
            for (int r = 0; r < 4; ++r) {
                const int l_glob = q0 + quad * 4 + r;
                const int relc = min(max(s_glob - l_glob, -MAXD), MAXD) + MAXD;
                S[t][r] = S[t][r] * 0.125f + rel_col[relc] + pt_col[pl_r[r] * PP + ps] + lx;
            }
        }

        // ---- online softmax (rows live in 16 lanes of each quad) ----
        float tmax[4];
#pragma unroll
        for (int r = 0; r < 4; ++r)
            tmax[r] = fmaxf(fmaxf(S[0][r], S[1][r]), fmaxf(S[2][r], S[3][r]));
#pragma unroll
        for (int mm = 1; mm < 16; mm <<= 1)
#pragma unroll
            for (int r = 0; r < 4; ++r) tmax[r] = fmaxf(tmax[r], __shfl_xor(tmax[r], mm));

        float alpha[4];
#pragma unroll
        for (int r = 0; r < 4; ++r) {
            float mn = fmaxf(m_i[r], tmax[r]);
            alpha[r] = __expf(m_i[r] - mn);
            m_i[r] = mn;
        }
#pragma unroll
        for (int t = 0; t < 4; ++t)
#pragma unroll
            for (int r = 0; r < 4; ++r) S[t][r] = __expf(S[t][r] - m_i[r]);

        float psum[4];
#pragma unroll
        for (int r = 0; r < 4; ++r) psum[r] = S[0][r] + S[1][r] + S[2][r] + S[3][r];
#pragma unroll
        for (int mm = 1; mm < 16; mm <<= 1)
#pragma unroll
            for (int r = 0; r < 4; ++r) psum[r] += __shfl_xor(psum[r], mm);
#pragma unroll
        for (int r = 0; r < 4; ++r) l_i[r] = l_i[r] * alpha[r] + psum[r];
#pragma unroll
        for (int t = 0; t < 4; ++t)
#pragma unroll
            for (int r = 0; r < 4; ++r) o_acc[t][r] *= alpha[r];

        // ---- P round-trip: C/D layout -> A-operand layout (wave-private region) ----
#pragma unroll
        for (int t = 0; t < 4; ++t)
#pragma unroll
            for (int r = 0; r < 4; ++r)
                Ps[w][quad * 4 + r][t * 16 + c] = __float2bfloat16(S[t][r]);

        short8 pa[2];
        pa[0] = *(const short8*)&Ps[w][c][quad * 8];
        pa[1] = *(const short8*)&Ps[w][c][quad * 8 + 32];

        // ---- O += P V ----
#pragma unroll
        for (int t = 0; t < 4; ++t) {
            short8 vf0, vf1;
#pragma unroll
            for (int j = 0; j < 8; ++j) {
                vf0[j] = Vs[quad * 8 + j][t * 16 + c];
                vf1[j] = Vs[quad * 8 + j + 32][t * 16 + c];
            }
            o_acc[t] = __builtin_amdgcn_mfma_f32_16x16x32_bf16(pa[0], vf0, o_acc[t], 0, 0, 0);
            o_acc[t] = __builtin_amdgcn_mfma_f32_16x16x32_bf16(pa[1], vf1, o_acc[t], 0, 0, 0);
        }
        __syncthreads();   // before next tile's Vs restage
    }

    // ---- epilogue: normalize + store ----
    float inv_l[4];
#pragma unroll
    for (int r = 0; r < 4; ++r) inv_l[r] = 1.f / l_i[r];
#pragma unroll
    for (int t = 0; t < 4; ++t)
#pragma unroll
        for (int r = 0; r < 4; ++r) {
            const int row = q0 + quad * 4 + r;
            O[((size_t)(b * LL + row)) * DD + h * DK + t * 16 + c] =
                __float2bfloat16(o_acc[t][r] * inv_l[r]);
        }
}

extern "C" void kernel_launch(void* const* d_in, const int* in_sizes, int n_in,
                              void* d_out, int out_size, void* d_ws, size_t ws_size,
                              hipStream_t stream) {
    const float* x          = (const float*)d_in[0];
    const int*   postag_ids = (const int*)d_in[1];
    const float* lex_mask   = (const float*)d_in[2];
    const float* ln1_g      = (const float*)d_in[3];
    const float* ln1_b      = (const float*)d_in[4];
    const float* Wq         = (const float*)d_in[5];
    const float* bq         = (const float*)d_in[6];
    const float* Wk         = (const float*)d_in[7];
    const float* bk         = (const float*)d_in[8];
    const float* Wv         = (const float*)d_in[9];
    const float* bv         = (const float*)d_in[10];
    const float* Wo         = (const float*)d_in[11];
    const float* bo         = (const float*)d_in[12];
    const float* rel_emb    = (const float*)d_in[13];
    const float* pt_table   = (const float*)d_in[14];
    const float* ln2_g      = (const float*)d_in[15];
    const float* ln2_b      = (const float*)d_in[16];
    const float* W1         = (const float*)d_in[17];
    const float* b1         = (const float*)d_in[18];
    const float* W2         = (const float*)d_in[19];
    const float* b2         = (const float*)d_in[20];

    const int M = BB * LL;            // 4096
    char* ws = (char*)d_ws;
    size_t off = 0;
    bf16* y_ln = (bf16*)(ws + off); off += (size_t)M * DD * 2;
    bf16* Qm   = (bf16*)(ws + off); off += (size_t)M * DD * 2;
    bf16* Km   = (bf16*)(ws + off); off += (size_t)M * DD * 2;
    bf16* Vm   = (bf16*)(ws + off); off += (size_t)M * DD * 2;
    bf16* attn = (bf16*)(ws + off); off += (size_t)M * DD * 2;
    bf16* h2   = (bf16*)(ws + off); off += (size_t)M * DD * 2;
    float* out1 = (float*)(ws + off); off += (size_t)M * DD * 4;
    bf16* ff1  = (bf16*)(ws + off); off += (size_t)M * FF_ * 2;

    // 1. LN1
    ln_kernel<float><<<M, 256, 0, stream>>>(x, ln1_g, ln1_b, 1e-6f, y_ln);

    // 2. Q,K,V projections
    dim3 gD(DD / 64, M / 64);
    gemm_kernel<0, false, bf16, bf16><<<gD, 256, 0, stream>>>(y_ln, Wq, bq, nullptr, Qm, M, DD, DD);
    gemm_kernel<0, false, bf16, bf16><<<gD, 256, 0, stream>>>(y_ln, Wk, bk, nullptr, Km, M, DD, DD);
    gemm_kernel<0, false, bf16, bf16><<<gD, 256, 0, stream>>>(y_ln, Wv, bv, nullptr, Vm, M, DD, DD);

    // 3. flash attention with fused biases (MFMA)
    flash_attn_kernel<<<dim3(LL / 64, HH, BB), 256, 0, stream>>>(
        Qm, Km, Vm, postag_ids, lex_mask, rel_emb, pt_table, attn);

    // 4. output projection + residual x
    gemm_kernel<2, false, bf16, float><<<gD, 256, 0, stream>>>(attn, Wo, bo, x, out1, M, DD, DD);

    // 5. LN2
    ln_kernel<float><<<M, 256, 0, stream>>>(out1, ln2_g, ln2_b, 1e-5f, h2);

    // 6. FF1 + exact GELU
    dim3 gF(FF_ / 64, M / 64);
    gemm_kernel<0, true, bf16, bf16><<<gF, 256, 0, stream>>>(h2, W1, b1, nullptr, ff1, M, FF_, DD);

    // 7. FF2 + residual(out1) -> d_out (fp32)
    gemm_kernel<2, false, bf16, float><<<gD, 256, 0, stream>>>(ff1, W2, b2, out1, (float*)d_out, M, DD, FF_);
}

// Round 4
// 380.869 us; speedup vs baseline: 11.3168x; 4.1910x over previous
//
#include <hip/hip_runtime.h>
#include <hip/hip_bf16.h>
#include <math.h>

typedef __hip_bfloat16 bf16;
typedef __attribute__((ext_vector_type(8))) short short8;
typedef __attribute__((ext_vector_type(4))) float f32x4;
typedef __attribute__((ext_vector_type(4))) int int4v;

#define BB 4
#define LL 1024
#define DD 768
#define HH 12
#define DK 64
#define FF_ 3072
#define PP 32
#define MAXD 256
#define QKVS 2304   // fused QKV row stride (Q at +0, K at +768, V at +1536)

__device__ inline float to_f(const bf16 v) { return __bfloat162float(v); }

// async global->LDS, 16B per lane. l must be wave-uniform; lane i lands at l + i*16.
__device__ __forceinline__ void async_load16(const void* g, void* l) {
    __builtin_amdgcn_global_load_lds(
        (const __attribute__((address_space(1))) unsigned int*)g,
        (__attribute__((address_space(3))) unsigned int*)l, 16, 0, 0);
}

// ---------------- LayerNorm (fp32 in, bf16 out) ----------------
__global__ __launch_bounds__(256) void ln_kernel(const float* __restrict__ x,
                                                 const float* __restrict__ g,
                                                 const float* __restrict__ b,
                                                 float eps,
                                                 bf16* __restrict__ y) {
    const int row = blockIdx.x;
    const int tid = threadIdx.x;
    const float* xr = x + (size_t)row * DD;

    float v[3];
    float s = 0.f, ss = 0.f;
#pragma unroll
    for (int i = 0; i < 3; ++i) {
        float t = xr[tid + i * 256];
        v[i] = t;
        s += t;
        ss += t * t;
    }
    __shared__ float rs[256], rss[256];
    rs[tid] = s; rss[tid] = ss;
    __syncthreads();
    for (int off = 128; off; off >>= 1) {
        if (tid < off) { rs[tid] += rs[tid + off]; rss[tid] += rss[tid + off]; }
        __syncthreads();
    }
    const float mean = rs[0] * (1.f / DD);
    const float var  = rss[0] * (1.f / DD) - mean * mean;
    const float inv  = rsqrtf(var + eps);
#pragma unroll
    for (int i = 0; i < 3; ++i) {
        int c = tid + i * 256;
        float o = (v[i] - mean) * inv * g[c] + b[c];
        y[(size_t)row * DD + c] = __float2bfloat16(o);
    }
}

// ---------------- transpose + fp32->bf16: W[K][N] -> Wt[N][K] ----------------
// grid (N/32, K/32), 256 threads
__global__ __launch_bounds__(256) void transpose_convert(const float* __restrict__ W,
                                                         bf16* __restrict__ Wt,
                                                         int K, int N) {
    __shared__ float tile[32][33];
    const int n0 = blockIdx.x * 32, k0 = blockIdx.y * 32;
    const int tx = threadIdx.x & 31, ty = threadIdx.x >> 5;  // ty 0..7
#pragma unroll
    for (int i = 0; i < 4; ++i) {
        int k = ty + i * 8;
        tile[k][tx] = W[(size_t)(k0 + k) * N + n0 + tx];
    }
    __syncthreads();
#pragma unroll
    for (int i = 0; i < 4; ++i) {
        int n = ty + i * 8;
        Wt[(size_t)(n0 + n) * K + k0 + tx] = __float2bfloat16(tile[tx][n]);
    }
}

// ---------------- bias pack: bqkv = [bq | bk | bv] ----------------
__global__ __launch_bounds__(256) void bias_pack(const float* __restrict__ bq,
                                                 const float* __restrict__ bk,
                                                 const float* __restrict__ bv,
                                                 float* __restrict__ dst) {
    int i = blockIdx.x * 256 + threadIdx.x;   // 0..2303
    float v = (i < 768) ? bq[i] : (i < 1536) ? bk[i - 768] : bv[i - 1536];
    dst[i] = v;
}

// ---------------- MFMA GEMM: C[M][N] = act(A[M][K] @ Bt[N][K]^T + bias) (+res) ----------------
// 128x128 tile, BK=32, 256 threads = 4 waves in 2x2; swizzled LDS (16B chunks) so
// global_load_lds staging (no pad allowed) still gives 2-way-only (free) frag reads.
template <int RES, bool GELU, typename OutT>
__global__ __launch_bounds__(256) void mfma_gemm_bt(const bf16* __restrict__ A,
                                                    const bf16* __restrict__ Bt,
                                                    const float* __restrict__ bias,
                                                    const float* __restrict__ res,
                                                    OutT* __restrict__ C,
                                                    int M, int N, int K) {
    __shared__ short As[4096];   // 128 rows x 32 bf16 (64B = 4 chunks of 16B), swizzled
    __shared__ short Bs[4096];

    const int bm = blockIdx.y * 128, bn = blockIdx.x * 128;
    const int tid = threadIdx.x;
    const int w = tid >> 6, lane = tid & 63;
    const int c16 = lane & 15, quad = lane >> 4;
    const int wy = w >> 1, wx = w & 1;

    // staging coords: chunk ci = w*2+j covers rows ci*16..+15; 4 lanes/row.
    const int srow_in = lane >> 2;              // 0..15 within chunk
    const int cg = (lane & 3) ^ quad;           // swizzled global chunk  (quad == (row>>2)&3 here)

    f32x4 acc[4][4];
#pragma unroll
    for (int i = 0; i < 4; ++i)
#pragma unroll
        for (int j = 0; j < 4; ++j) acc[i][j] = (f32x4)0.f;

    for (int k0 = 0; k0 < K; k0 += 32) {
#pragma unroll
        for (int j = 0; j < 2; ++j) {
            const int ci = w * 2 + j;
            const int row = ci * 16 + srow_in;
            async_load16(A + (size_t)(bm + row) * K + k0 + cg * 8, (char*)As + ci * 1024);
            async_load16(Bt + (size_t)(bn + row) * K + k0 + cg * 8, (char*)Bs + ci * 1024);
        }
        __syncthreads();

        short8 af[4], bf[4];
#pragma unroll
        for (int i = 0; i < 4; ++i) {
            const int ra = wy * 64 + i * 16 + c16;
            const int ca = quad ^ ((ra >> 2) & 3);
            af[i] = *(const short8*)((const char*)As + ra * 64 + ca * 16);
            const int rb = wx * 64 + i * 16 + c16;
            const int cb = quad ^ ((rb >> 2) & 3);
            bf[i] = *(const short8*)((const char*)Bs + rb * 64 + cb * 16);
        }
#pragma unroll
        for (int mi = 0; mi < 4; ++mi)
#pragma unroll
            for (int ni = 0; ni < 4; ++ni)
                acc[mi][ni] = __builtin_amdgcn_mfma_f32_16x16x32_bf16(af[mi], bf[ni], acc[mi][ni], 0, 0, 0);
        __syncthreads();
    }

    // epilogue: D row = quad*4+r, col = c16
#pragma unroll
    for (int mi = 0; mi < 4; ++mi) {
#pragma unroll
        for (int ni = 0; ni < 4; ++ni) {
            const int n = bn + wx * 64 + ni * 16 + c16;
            const float bv = bias[n];
#pragma unroll
            for (int r = 0; r < 4; ++r) {
                const int m = bm + wy * 64 + mi * 16 + quad * 4 + r;
                float v = acc[mi][ni][r] + bv;
                if (GELU) v = 0.5f * v * (1.f + erff(v * 0.70710678118f));
                if (RES == 2) v += res[(size_t)m * N + n];
                if constexpr (sizeof(OutT) == 2)
                    C[(size_t)m * N + n] = __float2bfloat16(v);
                else
                    C[(size_t)m * N + n] = v;
            }
        }
    }
}

// ---------------- Flash attention with MFMA (QKV fused buffer, row stride 2304) ----------------
__global__ __launch_bounds__(256) void flash_attn_kernel(
        const bf16* __restrict__ qkv,
        const int* __restrict__ postag, const float* __restrict__ lex,
        const float* __restrict__ rel_emb, const float* __restrict__ pt_table,
        bf16* __restrict__ O) {
    const int qt = blockIdx.x;
    const int h  = blockIdx.y;
    const int b  = blockIdx.z;
    const int tid  = threadIdx.x;
    const int w    = tid >> 6;
    const int lane = tid & 63;
    const int c    = lane & 15;
    const int quad = lane >> 4;

    __shared__ short Vs[64][66];
    __shared__ bf16  Ps[4][16][72];
    __shared__ float rel_col[513];
    __shared__ float pt_col[1024];
    __shared__ float lex_t[64];
    __shared__ int   ps_t[64];

    for (int i = tid; i < 513; i += 256)  rel_col[i] = rel_emb[i * HH + h];
    for (int i = tid; i < 1024; i += 256) pt_col[i]  = pt_table[i * HH + h];

    const int q0 = qt * 64 + w * 16;

    short8 qf[2];
    {
        const bf16* qp = qkv + ((size_t)(b * LL + q0 + c)) * QKVS + h * DK + quad * 8;
        qf[0] = *(const short8*)qp;
        qf[1] = *(const short8*)(qp + 32);
    }
    int pl_r[4];
#pragma unroll
    for (int r = 0; r < 4; ++r) pl_r[r] = postag[b * LL + q0 + quad * 4 + r];

    float m_i[4], l_i[4];
#pragma unroll
    for (int r = 0; r < 4; ++r) { m_i[r] = -1e30f; l_i[r] = 0.f; }
    f32x4 o_acc[4];
#pragma unroll
    for (int t = 0; t < 4; ++t) o_acc[t] = (f32x4)0.f;

    for (int s0 = 0; s0 < LL; s0 += 64) {
#pragma unroll
        for (int it = 0; it < 2; ++it) {
            int i = it * 256 + tid;
            int row = i >> 3, c8 = (i & 7) * 8;
            int4v v = *(const int4v*)(qkv + ((size_t)(b * LL + s0 + row)) * QKVS + 1536 + h * DK + c8);
            int* dst = (int*)&Vs[row][c8];
            dst[0] = v.x; dst[1] = v.y; dst[2] = v.z; dst[3] = v.w;
        }
        if (tid < 64) {
            lex_t[tid] = lex[b * LL + s0 + tid];
            ps_t[tid]  = postag[b * LL + s0 + tid];
        }
        __syncthreads();

        short8 kf[4][2];
#pragma unroll
        for (int t = 0; t < 4; ++t) {
            const bf16* kp = qkv + ((size_t)(b * LL + s0 + t * 16 + c)) * QKVS + 768 + h * DK + quad * 8;
            kf[t][0] = *(const short8*)kp;
            kf[t][1] = *(const short8*)(kp + 32);
        }

        f32x4 S[4];
#pragma unroll
        for (int t = 0; t < 4; ++t) {
            f32x4 a = (f32x4)0.f;
            a = __builtin_amdgcn_mfma_f32_16x16x32_bf16(qf[0], kf[t][0], a, 0, 0, 0);
            a = __builtin_amdgcn_mfma_f32_16x16x32_bf16(qf[1], kf[t][1], a, 0, 0, 0);
            S[t] = a;
        }

#pragma unroll
        for (int t = 0; t < 4; ++t) {
            const int s_loc  = t * 16 + c;
            const float lx   = lex_t[s_loc];
            const int   ps   = ps_t[s_loc];
            const int s_glob = s0 + s_loc;
#pragma unroll
            for (int r = 0; r < 4; ++r) {
                const int l_glob = q0 + quad * 4 + r;
                const int relc = min(max(s_glob - l_glob, -MAXD), MAXD) + MAXD;
                S[t][r] = S[t][r] * 0.125f + rel_col[relc] + pt_col[pl_r[r] * PP + ps] + lx;
            }
        }

        float tmax[4];
#pragma unroll
        for (int r = 0; r < 4; ++r)
            tmax[r] = fmaxf(fmaxf(S[0][r], S[1][r]), fmaxf(S[2][r], S[3][r]));
#pragma unroll
        for (int mm = 1; mm < 16; mm <<= 1)
#pragma unroll
            for (int r = 0; r < 4; ++r) tmax[r] = fmaxf(tmax[r], __shfl_xor(tmax[r], mm));

        float alpha[4];
#pragma unroll
        for (int r = 0; r < 4; ++r) {
            float mn = fmaxf(m_i[r], tmax[r]);
            alpha[r] = __expf(m_i[r] - mn);
            m_i[r] = mn;
        }
#pragma unroll
        for (int t = 0; t < 4; ++t)
#pragma unroll
            for (int r = 0; r < 4; ++r) S[t][r] = __expf(S[t][r] - m_i[r]);

        float psum[4];
#pragma unroll
        for (int r = 0; r < 4; ++r) psum[r] = S[0][r] + S[1][r] + S[2][r] + S[3][r];
#pragma unroll
        for (int mm = 1; mm < 16; mm <<= 1)
#pragma unroll
            for (int r = 0; r < 4; ++r) psum[r] += __shfl_xor(psum[r], mm);
#pragma unroll
        for (int r = 0; r < 4; ++r) l_i[r] = l_i[r] * alpha[r] + psum[r];
#pragma unroll
        for (int t = 0; t < 4; ++t)
#pragma unroll
            for (int r = 0; r < 4; ++r) o_acc[t][r] *= alpha[r];

#pragma unroll
        for (int t = 0; t < 4; ++t)
#pragma unroll
            for (int r = 0; r < 4; ++r)
                Ps[w][quad * 4 + r][t * 16 + c] = __float2bfloat16(S[t][r]);

        short8 pa[2];
        pa[0] = *(const short8*)&Ps[w][c][quad * 8];
        pa[1] = *(const short8*)&Ps[w][c][quad * 8 + 32];

#pragma unroll
        for (int t = 0; t < 4; ++t) {
            short8 vf0, vf1;
#pragma unroll
            for (int j = 0; j < 8; ++j) {
                vf0[j] = Vs[quad * 8 + j][t * 16 + c];
                vf1[j] = Vs[quad * 8 + j + 32][t * 16 + c];
            }
            o_acc[t] = __builtin_amdgcn_mfma_f32_16x16x32_bf16(pa[0], vf0, o_acc[t], 0, 0, 0);
            o_acc[t] = __builtin_amdgcn_mfma_f32_16x16x32_bf16(pa[1], vf1, o_acc[t], 0, 0, 0);
        }
        __syncthreads();
    }

    float inv_l[4];
#pragma unroll
    for (int r = 0; r < 4; ++r) inv_l[r] = 1.f / l_i[r];
#pragma unroll
    for (int t = 0; t < 4; ++t)
#pragma unroll
        for (int r = 0; r < 4; ++r) {
            const int row = q0 + quad * 4 + r;
            O[((size_t)(b * LL + row)) * DD + h * DK + t * 16 + c] =
                __float2bfloat16(o_acc[t][r] * inv_l[r]);
        }
}

extern "C" void kernel_launch(void* const* d_in, const int* in_sizes, int n_in,
                              void* d_out, int out_size, void* d_ws, size_t ws_size,
                              hipStream_t stream) {
    const float* x          = (const float*)d_in[0];
    const int*   postag_ids = (const int*)d_in[1];
    const float* lex_mask   = (const float*)d_in[2];
    const float* ln1_g      = (const float*)d_in[3];
    const float* ln1_b      = (const float*)d_in[4];
    const float* Wq         = (const float*)d_in[5];
    const float* bq         = (const float*)d_in[6];
    const float* Wk         = (const float*)d_in[7];
    const float* bk         = (const float*)d_in[8];
    const float* Wv         = (const float*)d_in[9];
    const float* bv         = (const float*)d_in[10];
    const float* Wo         = (const float*)d_in[11];
    const float* bo         = (const float*)d_in[12];
    const float* rel_emb    = (const float*)d_in[13];
    const float* pt_table   = (const float*)d_in[14];
    const float* ln2_g      = (const float*)d_in[15];
    const float* ln2_b      = (const float*)d_in[16];
    const float* W1         = (const float*)d_in[17];
    const float* b1         = (const float*)d_in[18];
    const float* W2         = (const float*)d_in[19];
    const float* b2         = (const float*)d_in[20];

    const int M = BB * LL;            // 4096
    char* ws = (char*)d_ws;
    size_t off = 0;
    bf16* y_ln  = (bf16*)(ws + off); off += (size_t)M * DD * 2;        // 6.3MB
    bf16* QKV   = (bf16*)(ws + off); off += (size_t)M * QKVS * 2;      // 18.9MB
    bf16* attn  = (bf16*)(ws + off); off += (size_t)M * DD * 2;        // 6.3MB
    bf16* h2    = (bf16*)(ws + off); off += (size_t)M * DD * 2;        // 6.3MB
    float* out1 = (float*)(ws + off); off += (size_t)M * DD * 4;       // 12.6MB
    bf16* ff1   = (bf16*)(ws + off); off += (size_t)M * FF_ * 2;       // 25.2MB
    bf16* WtQKV = (bf16*)(ws + off); off += (size_t)QKVS * DD * 2;     // 3.5MB
    bf16* WtO   = (bf16*)(ws + off); off += (size_t)DD * DD * 2;       // 1.2MB
    bf16* Wt1   = (bf16*)(ws + off); off += (size_t)FF_ * DD * 2;      // 4.7MB
    bf16* Wt2   = (bf16*)(ws + off); off += (size_t)DD * FF_ * 2;      // 4.7MB
    float* bqkv = (float*)(ws + off); off += (size_t)QKVS * 4;

    // 0. weight transposes (fp32 -> bf16, [K][N] -> [N][K]) + bias pack
    dim3 t_dd(DD / 32, DD / 32);
    transpose_convert<<<t_dd, 256, 0, stream>>>(Wq, WtQKV,                    DD, DD);
    transpose_convert<<<t_dd, 256, 0, stream>>>(Wk, WtQKV + (size_t)768 * DD, DD, DD);
    transpose_convert<<<t_dd, 256, 0, stream>>>(Wv, WtQKV + (size_t)1536 * DD, DD, DD);
    transpose_convert<<<t_dd, 256, 0, stream>>>(Wo, WtO, DD, DD);
    transpose_convert<<<dim3(FF_ / 32, DD / 32), 256, 0, stream>>>(W1, Wt1, DD, FF_);
    transpose_convert<<<dim3(DD / 32, FF_ / 32), 256, 0, stream>>>(W2, Wt2, FF_, DD);
    bias_pack<<<QKVS / 256, 256, 0, stream>>>(bq, bk, bv, bqkv);

    // 1. LN1
    ln_kernel<<<M, 256, 0, stream>>>(x, ln1_g, ln1_b, 1e-6f, y_ln);

    // 2. fused QKV projection  [4096 x 2304]
    mfma_gemm_bt<0, false, bf16><<<dim3(QKVS / 128, M / 128), 256, 0, stream>>>(
        y_ln, WtQKV, bqkv, nullptr, QKV, M, QKVS, DD);

    // 3. flash attention
    flash_attn_kernel<<<dim3(LL / 64, HH, BB), 256, 0, stream>>>(
        QKV, postag_ids, lex_mask, rel_emb, pt_table, attn);

    // 4. output projection + residual x -> fp32
    mfma_gemm_bt<2, false, float><<<dim3(DD / 128, M / 128), 256, 0, stream>>>(
        attn, WtO, bo, x, out1, M, DD, DD);

    // 5. LN2
    ln_kernel<<<M, 256, 0, stream>>>(out1, ln2_g, ln2_b, 1e-5f, h2);

    // 6. FF1 + exact GELU
    mfma_gemm_bt<0, true, bf16><<<dim3(FF_ / 128, M / 128), 256, 0, stream>>>(
        h2, Wt1, b1, nullptr, ff1, M, FF_, DD);

    // 7. FF2 + residual(out1) -> d_out fp32
    mfma_gemm_bt<2, false, float><<<dim3(DD / 128, M / 128), 256, 0, stream>>>(
        ff1, Wt2, b2, out1, (float*)d_out, M, DD, FF_);
}